// Round 6
// baseline (1805.279 us; speedup 1.0000x reference)
//
#include <hip/hip_runtime.h>
#include <cstdint>

typedef __bf16 bf16;

#define T_TOK 8192
#define IN_F  2048
#define OUT_F 2048
#define G_COLS 384    // 128 gate + 256 z
#define A2C 320       // 256 zw + 8 w + 1 one + 55 zero pad

// ---- workspace layout (bytes) ----
#define WS_G   0                   // fp32 G   8192*384*4 = 12582912
#define WS_A2  12582912            // fp32 A2f 8192*320*4 = 10485760
#define WS_B2  23068672            // fp32 B2f 2048*320*4 =  2621440
// total 25690112 B (~24.5 MiB)

// B2f[o][j]: j<256 -> u[e=j>>5][o][k=j&31]; 256..263 -> eb[j-256][o];
//            264 -> b[o]; else 0.
__global__ void prep_b2(const float* __restrict__ u, const float* __restrict__ eb,
                        const float* __restrict__ b, float* __restrict__ B2) {
  int i = blockIdx.x * 256 + threadIdx.x;
  const int nt = gridDim.x * 256;
  for (; i < OUT_F * A2C; i += nt) {
    const int o = i / A2C, j = i - o * A2C;
    float v;
    if (j < 256) {
      const int e = j >> 5, k = j & 31;
      v = u[((size_t)(e * OUT_F + o)) * 32 + k];
    } else if (j < 264) {
      v = eb[(size_t)(j - 256) * OUT_F + o];
    } else if (j == 264) {
      v = b[o];
    } else {
      v = 0.f;
    }
    B2[i] = v;
  }
}

// Plain fp32 vector-ALU tiled GEMM (verified R4 pipeline).
// PRE=false: C = x @ [gw;svh]^T -> G fp32 [8192 x 384]
// PRE=true : C = x @ W^T + A2f @ B2f^T -> out FP32 [8192 x 2048]
template <bool PRE>
__global__ __launch_bounds__(256) void vgemm(
    const float* __restrict__ x, const float* __restrict__ W,
    const float* __restrict__ gw, const float* __restrict__ svh,
    const float* __restrict__ A2, const float* __restrict__ B2,
    float* __restrict__ Gout, float* __restrict__ out) {
  __shared__ float As[64][37];
  __shared__ float Bs[64][37];
  const int tid = threadIdx.x;
  const int tx = tid & 15, ty = tid >> 4;
  const int gm0 = blockIdx.y * 64, gn0 = blockIdx.x * 64;
  const int N = PRE ? OUT_F : G_COLS;

  float acc[4][4] = {};

  // phase 1: K = IN_F over x and (W | gw/svh row-split); both B conventions
  // row-major [n][k] -> C = A @ B^T  (reference: x @ W.T)
  for (int k0 = 0; k0 < IN_F; k0 += 32) {
    __syncthreads();
#pragma unroll
    for (int it = 0; it < 2; ++it) {
      const int idx = it * 256 + tid;
      const int r = idx >> 3, c4 = (idx & 7) * 4;
      const float4 av = *(const float4*)(x + (size_t)(gm0 + r) * IN_F + k0 + c4);
      As[r][c4 + 0] = av.x; As[r][c4 + 1] = av.y;
      As[r][c4 + 2] = av.z; As[r][c4 + 3] = av.w;
      const int n = gn0 + r;
      const float* brow = PRE ? (W + (size_t)n * IN_F)
                              : (n < 128 ? gw + (size_t)n * IN_F
                                         : svh + (size_t)(n - 128) * IN_F);
      const float4 bv = *(const float4*)(brow + k0 + c4);
      Bs[r][c4 + 0] = bv.x; Bs[r][c4 + 1] = bv.y;
      Bs[r][c4 + 2] = bv.z; Bs[r][c4 + 3] = bv.w;
    }
    __syncthreads();
#pragma unroll 4
    for (int k = 0; k < 32; ++k) {
      float a[4], bb[4];
#pragma unroll
      for (int i = 0; i < 4; ++i) a[i] = As[4 * ty + i][k];
#pragma unroll
      for (int j = 0; j < 4; ++j) bb[j] = Bs[4 * tx + j][k];
#pragma unroll
      for (int i = 0; i < 4; ++i)
#pragma unroll
        for (int j = 0; j < 4; ++j) acc[i][j] += a[i] * bb[j];
    }
  }

  // phase 2 (PRE only): fold MoE + biases as 10 more K-tiles over A2f/B2f
  if (PRE) {
    for (int k0 = 0; k0 < A2C; k0 += 32) {
      __syncthreads();
#pragma unroll
      for (int it = 0; it < 2; ++it) {
        const int idx = it * 256 + tid;
        const int r = idx >> 3, c4 = (idx & 7) * 4;
        const float4 av = *(const float4*)(A2 + (size_t)(gm0 + r) * A2C + k0 + c4);
        As[r][c4 + 0] = av.x; As[r][c4 + 1] = av.y;
        As[r][c4 + 2] = av.z; As[r][c4 + 3] = av.w;
        const float4 bv = *(const float4*)(B2 + (size_t)(gn0 + r) * A2C + k0 + c4);
        Bs[r][c4 + 0] = bv.x; Bs[r][c4 + 1] = bv.y;
        Bs[r][c4 + 2] = bv.z; Bs[r][c4 + 3] = bv.w;
      }
      __syncthreads();
#pragma unroll 4
      for (int k = 0; k < 32; ++k) {
        float a[4], bb[4];
#pragma unroll
        for (int i = 0; i < 4; ++i) a[i] = As[4 * ty + i][k];
#pragma unroll
        for (int j = 0; j < 4; ++j) bb[j] = Bs[4 * tx + j][k];
#pragma unroll
        for (int i = 0; i < 4; ++i)
#pragma unroll
          for (int j = 0; j < 4; ++j) acc[i][j] += a[i] * bb[j];
      }
    }
  }

#pragma unroll
  for (int i = 0; i < 4; ++i)
#pragma unroll
    for (int j = 0; j < 4; ++j) {
      const size_t off = (size_t)(gm0 + 4 * ty + i) * N + (gn0 + 4 * tx + j);
      if (PRE) out[off] = acc[i][j];      // FP32 OUTPUT (the round-5 fix)
      else     Gout[off] = acc[i][j];
    }
}

// One wave per token: norms over 16-dim groups -> exact top-2 softmax -> A2f row.
__global__ void router_kernel(const float* __restrict__ G, float* __restrict__ A2) {
  const int wave = threadIdx.x >> 6, lane = threadIdx.x & 63;
  const int t = blockIdx.x * 4 + wave;
  const float* g = G + (size_t)t * G_COLS;
  const float g1 = g[lane], g2 = g[lane + 64];
  float s1 = g1 * g1, s2 = g2 * g2;
#pragma unroll
  for (int off = 1; off < 16; off <<= 1) {
    s1 += __shfl_xor(s1, off, 64);
    s2 += __shfl_xor(s2, off, 64);
  }
  float lg[8];
#pragma unroll
  for (int e = 0; e < 4; ++e) {
    lg[e]     = sqrtf(__shfl(s1, e * 16, 64));
    lg[e + 4] = sqrtf(__shfl(s2, e * 16, 64));
  }
  int i1 = 0; float l1 = lg[0];
#pragma unroll
  for (int e = 1; e < 8; ++e) if (lg[e] > l1) { l1 = lg[e]; i1 = e; }
  int i2 = -1; float l2 = -1e30f;
#pragma unroll
  for (int e = 0; e < 8; ++e) if (e != i1 && lg[e] > l2) { l2 = lg[e]; i2 = e; }
  const float w1 = 1.f / (1.f + expf(l2 - l1));  // exact top-2 softmax renorm
  const float w2 = 1.f - w1;

  float* a2 = A2 + (size_t)t * A2C;
  const float* z = g + 128;
#pragma unroll
  for (int c0 = 0; c0 < A2C; c0 += 64) {
    const int c = c0 + lane;
    float v;
    if (c < 256) {
      const int we = c >> 5;
      const float wsel = (we == i1) ? w1 : ((we == i2) ? w2 : 0.f);
      v = z[c] * wsel;
    } else if (c < 264) {
      const int we = c - 256;
      v = (we == i1) ? w1 : ((we == i2) ? w2 : 0.f);
    } else if (c == 264) {
      v = 1.f;
    } else {
      v = 0.f;
    }
    a2[c] = v;
  }
}

extern "C" void kernel_launch(void* const* d_in, const int* in_sizes, int n_in,
                              void* d_out, int out_size, void* d_ws, size_t ws_size,
                              hipStream_t stream) {
  // size-based dispatch (immune to input ordering); u/svh share 524288:
  // first occurrence = u, second = svh (setup_inputs dict order).
  const float *x = nullptr, *W = nullptr, *b = nullptr, *gw = nullptr;
  const float *u = nullptr, *svh = nullptr, *eb = nullptr;
  int seen524 = 0;
  for (int i = 0; i < n_in; ++i) {
    switch (in_sizes[i]) {
      case 16777216: x  = (const float*)d_in[i]; break;
      case 4194304:  W  = (const float*)d_in[i]; break;
      case 2048:     b  = (const float*)d_in[i]; break;
      case 262144:   gw = (const float*)d_in[i]; break;
      case 524288:   if (seen524++ == 0) u = (const float*)d_in[i];
                     else                svh = (const float*)d_in[i];
                     break;
      case 16384:    eb = (const float*)d_in[i]; break;
      default: break;  // top_k (size 1)
    }
  }
  float* out = (float*)d_out;   // FP32 output — reference returns float32

  char* ws = (char*)d_ws;
  float* G   = (float*)(ws + WS_G);
  float* A2f = (float*)(ws + WS_A2);
  float* B2f = (float*)(ws + WS_B2);

  prep_b2<<<256, 256, 0, stream>>>(u, eb, b, B2f);

  // G = x @ [gw;svh]^T   [8192 x 384] fp32
  vgemm<false><<<dim3(G_COLS / 64, T_TOK / 64), 256, 0, stream>>>(
      x, nullptr, gw, svh, nullptr, nullptr, G, nullptr);

  router_kernel<<<T_TOK / 4, 256, 0, stream>>>(G, A2f);

  // out = x @ W^T + A2f @ B2f^T   (pre + moe + both biases), fp32 store
  vgemm<true><<<dim3(OUT_F / 64, T_TOK / 64), 256, 0, stream>>>(
      x, W, nullptr, nullptr, A2f, B2f, nullptr, out);
}

// Round 8
// 407.383 us; speedup vs baseline: 4.4314x; 4.4314x over previous
//
#include <hip/hip_runtime.h>
#include <cstdint>

typedef __bf16 bf16;
typedef __attribute__((ext_vector_type(8))) __bf16 bf16x8;
typedef __attribute__((ext_vector_type(4))) __bf16 bf16x4;
typedef __attribute__((ext_vector_type(4))) float f32x4;

#define T_TOK 8192
#define IN_F  2048
#define OUT_F 2048
#define Z_COLS 256    // svh rows (8 experts x 32)
#define A2C 320       // 256 zw + 8 w + 1 one + 55 zero pad
#define K2_TOT 2368   // 2048 + 320

// ---- workspace layout (bytes) ----
#define WS_XB  0                      // bf16 xb   8192*2048*2 = 33554432
#define WS_GG  33554432               // fp32 Gg   8192*128*4  =  4194304
#define WS_Z   37748736               // fp32 Z    8192*256*4  =  8388608
#define WS_A2  46137344               // bf16 A2   8192*320*2  =  5242880
#define WS_B2  51380224               // bf16 B2   2048*320*2  =  1310720
#define WS_WZ  52690944               // bf16 Wz   256*2048*2  =  1048576
#define WS_WB  53739520               // bf16 Wb   2048*2048*2 =  8388608
// total 62128128 B

// Convert fp32 inputs to bf16 workspace tensors (gate_w stays fp32 — router
// selection needs fp32 logits; round-7 failure was bf16-logit top-2 flips).
__global__ void prep_kernel(const float* __restrict__ x, const float* __restrict__ W,
                            const float* __restrict__ svh,
                            const float* __restrict__ u, const float* __restrict__ eb,
                            const float* __restrict__ b,
                            bf16* __restrict__ xb, bf16* __restrict__ Wb,
                            bf16* __restrict__ Wz, bf16* __restrict__ B2) {
  const int idx = blockIdx.x * 256 + threadIdx.x;
  const int nt  = gridDim.x * 256;

  const int nx4 = (T_TOK * IN_F) / 4;
  for (int i = idx; i < nx4; i += nt) {
    const float4 v = ((const float4*)x)[i];
    bf16x4 o = {(bf16)v.x, (bf16)v.y, (bf16)v.z, (bf16)v.w};
    *(bf16x4*)&xb[(size_t)i * 4] = o;
  }
  const int nw4 = (OUT_F * IN_F) / 4;
  for (int i = idx; i < nw4; i += nt) {
    const float4 v = ((const float4*)W)[i];
    bf16x4 o = {(bf16)v.x, (bf16)v.y, (bf16)v.z, (bf16)v.w};
    *(bf16x4*)&Wb[(size_t)i * 4] = o;
  }
  const int nz4 = (Z_COLS * IN_F) / 4;   // svh flat [256][2048]
  for (int i = idx; i < nz4; i += nt) {
    const float4 v = ((const float4*)svh)[i];
    bf16x4 o = {(bf16)v.x, (bf16)v.y, (bf16)v.z, (bf16)v.w};
    *(bf16x4*)&Wz[(size_t)i * 4] = o;
  }
  // B2[o][j]: j<256 -> u[e=j>>5][o][k=j&31]; 256..263 -> eb[j-256][o]; 264 -> b[o]; else 0
  for (int i = idx; i < OUT_F * A2C; i += nt) {
    const int o = i / A2C, j = i - o * A2C;
    float v;
    if (j < 256) {
      const int e = j >> 5, k = j & 31;
      v = u[((size_t)(e * OUT_F + o)) * 32 + k];
    } else if (j < 264) {
      v = eb[(size_t)(j - 256) * OUT_F + o];
    } else if (j == 264) {
      v = b[o];
    } else {
      v = 0.f;
    }
    B2[i] = (bf16)v;
  }
}

// fp32 VALU GEMM (R6-verified): Gg = x @ gw^T  [8192 x 128]
__global__ __launch_bounds__(256) void vgemm_gate(
    const float* __restrict__ x, const float* __restrict__ gw,
    float* __restrict__ Gout) {
  __shared__ float As[64][37];
  __shared__ float Bs[64][37];
  const int tid = threadIdx.x;
  const int tx = tid & 15, ty = tid >> 4;
  const int gm0 = blockIdx.y * 64, gn0 = blockIdx.x * 64;

  float acc[4][4] = {};
  for (int k0 = 0; k0 < IN_F; k0 += 32) {
    __syncthreads();
#pragma unroll
    for (int it = 0; it < 2; ++it) {
      const int idx = it * 256 + tid;
      const int r = idx >> 3, c4 = (idx & 7) * 4;
      const float4 av = *(const float4*)(x + (size_t)(gm0 + r) * IN_F + k0 + c4);
      As[r][c4 + 0] = av.x; As[r][c4 + 1] = av.y;
      As[r][c4 + 2] = av.z; As[r][c4 + 3] = av.w;
      const float4 bv = *(const float4*)(gw + (size_t)(gn0 + r) * IN_F + k0 + c4);
      Bs[r][c4 + 0] = bv.x; Bs[r][c4 + 1] = bv.y;
      Bs[r][c4 + 2] = bv.z; Bs[r][c4 + 3] = bv.w;
    }
    __syncthreads();
#pragma unroll 4
    for (int k = 0; k < 32; ++k) {
      float a[4], bb[4];
#pragma unroll
      for (int i = 0; i < 4; ++i) a[i] = As[4 * ty + i][k];
#pragma unroll
      for (int j = 0; j < 4; ++j) bb[j] = Bs[4 * tx + j][k];
#pragma unroll
      for (int i = 0; i < 4; ++i)
#pragma unroll
        for (int j = 0; j < 4; ++j) acc[i][j] += a[i] * bb[j];
    }
  }
#pragma unroll
  for (int i = 0; i < 4; ++i)
#pragma unroll
    for (int j = 0; j < 4; ++j)
      Gout[(size_t)(gm0 + 4 * ty + i) * 128 + (gn0 + 4 * tx + j)] = acc[i][j];
}

// bf16 MFMA GEMM, fp32 out (R7 core). A rows [M x Ktot]: k<K1 from A0 else A1.
template <int BM, int BN>
__global__ __launch_bounds__(256, 2) void gemm_bt(
    const bf16* __restrict__ A0, int lda0, const bf16* __restrict__ A1, int lda1,
    const bf16* __restrict__ B0, int ldb0, const bf16* __restrict__ B1, int ldb1,
    float* __restrict__ Cout, int M, int N, int K1, int Ktot) {
  constexpr int BK = 64;
  __shared__ __align__(16) bf16 As[BM * BK];
  __shared__ __align__(16) bf16 Bs[BN * BK];

  const int tid  = threadIdx.x;
  const int lane = tid & 63;
  const int ml   = lane & 15;
  const int q    = lane >> 4;
  const int wave = tid >> 6;

  const int gm0 = blockIdx.y * BM;
  const int gn0 = blockIdx.x * BN;

  constexpr int FM = BM / 32;
  constexpr int FN = BN / 32;
  const int wr  = wave >> 1, wc = wave & 1;
  const int wm0 = wr * (BM / 2);
  const int wn0 = wc * (BN / 2);

  f32x4 acc[FM][FN];
  const f32x4 zero = {0.f, 0.f, 0.f, 0.f};
#pragma unroll
  for (int i = 0; i < FM; ++i)
#pragma unroll
    for (int j = 0; j < FN; ++j) acc[i][j] = zero;

  constexpr int NCA = BM * 8 / 256;
  constexpr int NCB = BN * 8 / 256;

  const int nkt = Ktot / BK;
  for (int kt = 0; kt < nkt; ++kt) {
    const int k0 = kt * BK;
    const bf16* Ap; int lda, ka;
    const bf16* Bp; int ldb, kb;
    if (k0 < K1) { Ap = A0; lda = lda0; ka = k0; Bp = B0; ldb = ldb0; kb = k0; }
    else         { Ap = A1; lda = lda1; ka = k0 - K1; Bp = B1; ldb = ldb1; kb = k0 - K1; }

    bf16x8 ra[NCA], rb[NCB];
#pragma unroll
    for (int it = 0; it < NCA; ++it) {
      const int C = it * 256 + tid;
      const int m = C >> 3, c = C & 7;
      ra[it] = *(const bf16x8*)(Ap + (size_t)(gm0 + m) * lda + ka + c * 8);
    }
#pragma unroll
    for (int it = 0; it < NCB; ++it) {
      const int C = it * 256 + tid;
      const int n = C >> 3, c = C & 7;
      rb[it] = *(const bf16x8*)(Bp + (size_t)(gn0 + n) * ldb + kb + c * 8);
    }

    __syncthreads();

#pragma unroll
    for (int it = 0; it < NCA; ++it) {
      const int C = it * 256 + tid;
      const int m = C >> 3, c = C & 7;
      *(bf16x8*)&As[(m * 8 + (c ^ (m & 7))) * 8] = ra[it];
    }
#pragma unroll
    for (int it = 0; it < NCB; ++it) {
      const int C = it * 256 + tid;
      const int n = C >> 3, c = C & 7;
      *(bf16x8*)&Bs[(n * 8 + (c ^ (n & 7))) * 8] = rb[it];
    }

    __syncthreads();

#pragma unroll
    for (int s = 0; s < 2; ++s) {
      bf16x8 af[FM], bfr[FN];
#pragma unroll
      for (int i = 0; i < FM; ++i) {
        const int m = wm0 + i * 16 + ml;
        const int j = (s * 4 + q) ^ (m & 7);
        af[i] = *(const bf16x8*)&As[(m * 8 + j) * 8];
      }
#pragma unroll
      for (int jn = 0; jn < FN; ++jn) {
        const int n = wn0 + jn * 16 + ml;
        const int j = (s * 4 + q) ^ (n & 7);
        bfr[jn] = *(const bf16x8*)&Bs[(n * 8 + j) * 8];
      }
#pragma unroll
      for (int i = 0; i < FM; ++i)
#pragma unroll
        for (int jn = 0; jn < FN; ++jn)
          acc[i][jn] = __builtin_amdgcn_mfma_f32_16x16x32_bf16(af[i], bfr[jn], acc[i][jn], 0, 0, 0);
    }
  }

#pragma unroll
  for (int i = 0; i < FM; ++i) {
#pragma unroll
    for (int jn = 0; jn < FN; ++jn) {
      const int row = gm0 + wm0 + i * 16 + q * 4;
      const int col = gn0 + wn0 + jn * 16 + ml;
#pragma unroll
      for (int r = 0; r < 4; ++r)
        Cout[(size_t)(row + r) * N + col] = acc[i][jn][r];
    }
  }
}

// One wave per token: fp32 gate logits -> exact top-2 softmax -> bf16 A2 row.
__global__ void router_kernel(const float* __restrict__ Gg, const float* __restrict__ Z,
                              bf16* __restrict__ A2) {
  const int wave = threadIdx.x >> 6, lane = threadIdx.x & 63;
  const int t = blockIdx.x * 4 + wave;
  const float* g = Gg + (size_t)t * 128;
  const float g1 = g[lane], g2 = g[lane + 64];
  float s1 = g1 * g1, s2 = g2 * g2;
#pragma unroll
  for (int off = 1; off < 16; off <<= 1) {
    s1 += __shfl_xor(s1, off, 64);
    s2 += __shfl_xor(s2, off, 64);
  }
  float lg[8];
#pragma unroll
  for (int e = 0; e < 4; ++e) {
    lg[e]     = sqrtf(__shfl(s1, e * 16, 64));
    lg[e + 4] = sqrtf(__shfl(s2, e * 16, 64));
  }
  int i1 = 0; float l1 = lg[0];
#pragma unroll
  for (int e = 1; e < 8; ++e) if (lg[e] > l1) { l1 = lg[e]; i1 = e; }
  int i2 = -1; float l2 = -1e30f;
#pragma unroll
  for (int e = 0; e < 8; ++e) if (e != i1 && lg[e] > l2) { l2 = lg[e]; i2 = e; }
  const float w1 = 1.f / (1.f + expf(l2 - l1));  // exact top-2 softmax renorm
  const float w2 = 1.f - w1;

  bf16* a2 = A2 + (size_t)t * A2C;
  const float* z = Z + (size_t)t * Z_COLS;
#pragma unroll
  for (int c0 = 0; c0 < A2C; c0 += 64) {
    const int c = c0 + lane;
    float v;
    if (c < 256) {
      const int we = c >> 5;
      const float wsel = (we == i1) ? w1 : ((we == i2) ? w2 : 0.f);
      v = z[c] * wsel;
    } else if (c < 264) {
      const int we = c - 256;
      v = (we == i1) ? w1 : ((we == i2) ? w2 : 0.f);
    } else if (c == 264) {
      v = 1.f;
    } else {
      v = 0.f;
    }
    a2[c] = (bf16)v;
  }
}

extern "C" void kernel_launch(void* const* d_in, const int* in_sizes, int n_in,
                              void* d_out, int out_size, void* d_ws, size_t ws_size,
                              hipStream_t stream) {
  // size-based dispatch; u/svh share 524288: first = u, second = svh (dict order)
  const float *x = nullptr, *W = nullptr, *b = nullptr, *gw = nullptr;
  const float *u = nullptr, *svh = nullptr, *eb = nullptr;
  int seen524 = 0;
  for (int i = 0; i < n_in; ++i) {
    switch (in_sizes[i]) {
      case 16777216: x  = (const float*)d_in[i]; break;
      case 4194304:  W  = (const float*)d_in[i]; break;
      case 2048:     b  = (const float*)d_in[i]; break;
      case 262144:   gw = (const float*)d_in[i]; break;
      case 524288:   if (seen524++ == 0) u = (const float*)d_in[i];
                     else                svh = (const float*)d_in[i];
                     break;
      case 16384:    eb = (const float*)d_in[i]; break;
      default: break;  // top_k (size 1)
    }
  }
  float* out = (float*)d_out;   // fp32 output (confirmed round 6)

  char* ws = (char*)d_ws;
  bf16*  xb = (bf16*)(ws + WS_XB);
  float* Gg = (float*)(ws + WS_GG);
  float* Z  = (float*)(ws + WS_Z);
  bf16*  A2 = (bf16*)(ws + WS_A2);
  bf16*  B2 = (bf16*)(ws + WS_B2);
  bf16*  Wz = (bf16*)(ws + WS_WZ);
  bf16*  Wb = (bf16*)(ws + WS_WB);

  prep_kernel<<<1024, 256, 0, stream>>>(x, W, svh, u, eb, b, xb, Wb, Wz, B2);

  // Gate logits in fp32 (router selection must match np's fp32 top-2)
  vgemm_gate<<<dim3(2, T_TOK / 64), 256, 0, stream>>>(x, gw, Gg);

  // Z = xb @ Wz^T  [8192 x 256] fp32 (bf16 precision fine: feeds moe scaled term)
  gemm_bt<64, 128><<<dim3(Z_COLS / 128, T_TOK / 64), 256, 0, stream>>>(
      xb, IN_F, xb, IN_F, Wz, IN_F, Wz, IN_F, Z, T_TOK, Z_COLS, IN_F, IN_F);

  router_kernel<<<T_TOK / 4, 256, 0, stream>>>(Gg, Z, A2);

  // out = [xb | A2] @ [Wb | B2]^T   (pre + moe + both biases fused), fp32 store
  gemm_bt<128, 128><<<dim3(OUT_F / 128, T_TOK / 128), 256, 0, stream>>>(
      xb, IN_F, A2, A2C, Wb, IN_F, B2, A2C, out, T_TOK, OUT_F, IN_F, K2_TOT);
}

// Round 9
// 388.428 us; speedup vs baseline: 4.6476x; 1.0488x over previous
//
#include <hip/hip_runtime.h>
#include <cstdint>

typedef __bf16 bf16;
typedef __attribute__((ext_vector_type(8))) __bf16 bf16x8;
typedef __attribute__((ext_vector_type(4))) __bf16 bf16x4;
typedef __attribute__((ext_vector_type(4))) float f32x4;

#define T_TOK 8192
#define IN_F  2048
#define OUT_F 2048
#define Z_COLS 256    // svh rows (8 experts x 32)
#define A2C 320       // 256 zw + 8 w + 1 one + 55 zero pad
#define K2_TOT 2368   // 2048 + 320
#define GATE_KS 4     // split-K slices for fp32 gate GEMM

// ---- workspace layout (bytes) ----
#define WS_XB  0                      // bf16 xb   8192*2048*2 = 33554432
#define WS_GG  33554432               // fp32 Gg   8192*128*4  =  4194304 (atomic acc)
#define WS_A2  37748736               // bf16 A2   8192*320*2  =  5242880
#define WS_B2  42991616               // bf16 B2   2048*320*2  =  1310720
#define WS_WZ  44302336               // bf16 Wz   256*2048*2  =  1048576
#define WS_WB  45350912               // bf16 Wb   2048*2048*2 =  8388608
// total 53739520 B (< 62652416 known-good high-water)

// async 16B global->LDS; LDS dest is wave-uniform base, HW scatters lane i at
// base + i*16 (m104/m108). R1-proven incantation.
__device__ __forceinline__ void async_cp16(const bf16* g, bf16* l) {
  __builtin_amdgcn_global_load_lds(
      (const __attribute__((address_space(1))) void*)reinterpret_cast<uintptr_t>(g),
      (__attribute__((address_space(3))) void*)(uint32_t)reinterpret_cast<uintptr_t>(l),
      16, 0, 0);
}

// Convert fp32 inputs to bf16 workspace tensors (gate_w stays fp32: router
// selection needs fp32 logits — R7 failure was bf16-logit top-2 flips).
__global__ void prep_kernel(const float* __restrict__ x, const float* __restrict__ W,
                            const float* __restrict__ svh,
                            const float* __restrict__ u, const float* __restrict__ eb,
                            const float* __restrict__ b,
                            bf16* __restrict__ xb, bf16* __restrict__ Wb,
                            bf16* __restrict__ Wz, bf16* __restrict__ B2) {
  const int idx = blockIdx.x * 256 + threadIdx.x;
  const int nt  = gridDim.x * 256;

  const int nx4 = (T_TOK * IN_F) / 4;
  for (int i = idx; i < nx4; i += nt) {
    const float4 v = ((const float4*)x)[i];
    bf16x4 o = {(bf16)v.x, (bf16)v.y, (bf16)v.z, (bf16)v.w};
    *(bf16x4*)&xb[(size_t)i * 4] = o;
  }
  const int nw4 = (OUT_F * IN_F) / 4;
  for (int i = idx; i < nw4; i += nt) {
    const float4 v = ((const float4*)W)[i];
    bf16x4 o = {(bf16)v.x, (bf16)v.y, (bf16)v.z, (bf16)v.w};
    *(bf16x4*)&Wb[(size_t)i * 4] = o;
  }
  const int nz4 = (Z_COLS * IN_F) / 4;   // svh flat [256][2048]
  for (int i = idx; i < nz4; i += nt) {
    const float4 v = ((const float4*)svh)[i];
    bf16x4 o = {(bf16)v.x, (bf16)v.y, (bf16)v.z, (bf16)v.w};
    *(bf16x4*)&Wz[(size_t)i * 4] = o;
  }
  // B2[o][j]: j<256 -> u[e=j>>5][o][k=j&31]; 256..263 -> eb[j-256][o]; 264 -> b[o]; else 0
  for (int i = idx; i < OUT_F * A2C; i += nt) {
    const int o = i / A2C, j = i - o * A2C;
    float v;
    if (j < 256) {
      const int e = j >> 5, k = j & 31;
      v = u[((size_t)(e * OUT_F + o)) * 32 + k];
    } else if (j < 264) {
      v = eb[(size_t)(j - 256) * OUT_F + o];
    } else if (j == 264) {
      v = b[o];
    } else {
      v = 0.f;
    }
    B2[i] = (bf16)v;
  }
}

// fp32 VALU gate GEMM, split-K x4 (blockIdx.z), atomicAdd epilogue into Gg.
// Gg must be zeroed before launch. Grid dim3(2, 128, 4) = 1024 blocks.
__global__ __launch_bounds__(256) void vgemm_gate(
    const float* __restrict__ x, const float* __restrict__ gw,
    float* __restrict__ Gg) {
  __shared__ float As[64][37];
  __shared__ float Bs[64][37];
  const int tid = threadIdx.x;
  const int tx = tid & 15, ty = tid >> 4;
  const int gm0 = blockIdx.y * 64, gn0 = blockIdx.x * 64;
  const int kbeg = blockIdx.z * (IN_F / GATE_KS);
  const int kend = kbeg + (IN_F / GATE_KS);

  float acc[4][4] = {};
  for (int k0 = kbeg; k0 < kend; k0 += 32) {
    __syncthreads();
#pragma unroll
    for (int it = 0; it < 2; ++it) {
      const int idx = it * 256 + tid;
      const int r = idx >> 3, c4 = (idx & 7) * 4;
      const float4 av = *(const float4*)(x + (size_t)(gm0 + r) * IN_F + k0 + c4);
      As[r][c4 + 0] = av.x; As[r][c4 + 1] = av.y;
      As[r][c4 + 2] = av.z; As[r][c4 + 3] = av.w;
      const float4 bv = *(const float4*)(gw + (size_t)(gn0 + r) * IN_F + k0 + c4);
      Bs[r][c4 + 0] = bv.x; Bs[r][c4 + 1] = bv.y;
      Bs[r][c4 + 2] = bv.z; Bs[r][c4 + 3] = bv.w;
    }
    __syncthreads();
#pragma unroll 4
    for (int k = 0; k < 32; ++k) {
      float a[4], bb[4];
#pragma unroll
      for (int i = 0; i < 4; ++i) a[i] = As[4 * ty + i][k];
#pragma unroll
      for (int j = 0; j < 4; ++j) bb[j] = Bs[4 * tx + j][k];
#pragma unroll
      for (int i = 0; i < 4; ++i)
#pragma unroll
        for (int j = 0; j < 4; ++j) acc[i][j] += a[i] * bb[j];
    }
  }
#pragma unroll
  for (int i = 0; i < 4; ++i)
#pragma unroll
    for (int j = 0; j < 4; ++j)
      atomicAdd(&Gg[(size_t)(gm0 + 4 * ty + i) * 128 + (gn0 + 4 * tx + j)],
                acc[i][j]);
}

// bf16 MFMA GEMM (async global_load_lds staging, m97 rung). C = A @ B^T.
// A rows [M x Ktot]: k<K1 from A0 (ld lda0) else A1 (ld lda1, col k-K1); B same.
// LDS row-major [rows][8 x 16B chunks], chunk pos XOR-swizzled by (row&7).
template <int BM, int BN, bool OUTBF>
__global__ __launch_bounds__(256, 2) void gemm_bt(
    const bf16* __restrict__ A0, int lda0, const bf16* __restrict__ A1, int lda1,
    const bf16* __restrict__ B0, int ldb0, const bf16* __restrict__ B1, int ldb1,
    void* __restrict__ Cout, int ldc, int K1, int Ktot) {
  constexpr int BK = 64;
  __shared__ __align__(16) bf16 As[BM * BK];
  __shared__ __align__(16) bf16 Bs[BN * BK];

  const int tid  = threadIdx.x;
  const int lane = tid & 63;
  const int ml   = lane & 15;
  const int q    = lane >> 4;
  const int wave = tid >> 6;

  const int gm0 = blockIdx.y * BM;
  const int gn0 = blockIdx.x * BN;

  constexpr int FM = BM / 32;
  constexpr int FN = BN / 32;
  const int wr  = wave >> 1, wc = wave & 1;
  const int wm0 = wr * (BM / 2);
  const int wn0 = wc * (BN / 2);

  f32x4 acc[FM][FN];
  const f32x4 zero = {0.f, 0.f, 0.f, 0.f};
#pragma unroll
  for (int i = 0; i < FM; ++i)
#pragma unroll
    for (int j = 0; j < FN; ++j) acc[i][j] = zero;

  constexpr int NCA = BM * 8 / 256;  // staging instrs per thread (A)
  constexpr int NCB = BN * 8 / 256;

  const int nkt = Ktot / BK;
  for (int kt = 0; kt < nkt; ++kt) {
    const int k0 = kt * BK;
    const bf16* Ap; int lda, ka;
    const bf16* Bp; int ldb, kb;
    if (k0 < K1) { Ap = A0; lda = lda0; ka = k0; Bp = B0; ldb = ldb0; kb = k0; }
    else         { Ap = A1; lda = lda1; ka = k0 - K1; Bp = B1; ldb = ldb1; kb = k0 - K1; }

    __syncthreads();  // all waves done reading previous tile's LDS

#pragma unroll
    for (int it = 0; it < NCA; ++it) {
      const int Cb = it * 256 + wave * 64;   // wave-uniform chunk base
      const int C  = Cb + lane;
      const int m  = C >> 3;
      const int jg = (C & 7) ^ (m & 7);      // un-swizzle on global side
      async_cp16(Ap + (size_t)(gm0 + m) * lda + ka + jg * 8, &As[Cb * 8]);
    }
#pragma unroll
    for (int it = 0; it < NCB; ++it) {
      const int Cb = it * 256 + wave * 64;
      const int C  = Cb + lane;
      const int n  = C >> 3;
      const int jg = (C & 7) ^ (n & 7);
      async_cp16(Bp + (size_t)(gn0 + n) * ldb + kb + jg * 8, &Bs[Cb * 8]);
    }

    __syncthreads();  // compiler drains vmcnt before s_barrier -> LDS visible

#pragma unroll
    for (int s = 0; s < 2; ++s) {
      bf16x8 af[FM], bfr[FN];
#pragma unroll
      for (int i = 0; i < FM; ++i) {
        const int m = wm0 + i * 16 + ml;
        const int j = (s * 4 + q) ^ (m & 7);
        af[i] = *(const bf16x8*)&As[(m * 8 + j) * 8];
      }
#pragma unroll
      for (int jn = 0; jn < FN; ++jn) {
        const int n = wn0 + jn * 16 + ml;
        const int j = (s * 4 + q) ^ (n & 7);
        bfr[jn] = *(const bf16x8*)&Bs[(n * 8 + j) * 8];
      }
#pragma unroll
      for (int i = 0; i < FM; ++i)
#pragma unroll
        for (int jn = 0; jn < FN; ++jn)
          acc[i][jn] = __builtin_amdgcn_mfma_f32_16x16x32_bf16(af[i], bfr[jn], acc[i][jn], 0, 0, 0);
    }
  }

  // C/D layout: col=lane&15, row=(lane>>4)*4+reg
#pragma unroll
  for (int i = 0; i < FM; ++i) {
#pragma unroll
    for (int jn = 0; jn < FN; ++jn) {
      const int row = gm0 + wm0 + i * 16 + q * 4;
      const int col = gn0 + wn0 + jn * 16 + ml;
#pragma unroll
      for (int r = 0; r < 4; ++r) {
        if (OUTBF)
          ((bf16*)Cout)[(size_t)(row + r) * ldc + col] = (bf16)acc[i][jn][r];
        else
          ((float*)Cout)[(size_t)(row + r) * ldc + col] = acc[i][jn][r];
      }
    }
  }
}

// One wave per token: fp32 gate logits -> exact top-2 softmax; scale the bf16
// z values already sitting in A2[t][0:256] in-place; fill cols 256..319.
__global__ void router_kernel(const float* __restrict__ Gg, bf16* __restrict__ A2) {
  const int wave = threadIdx.x >> 6, lane = threadIdx.x & 63;
  const int t = blockIdx.x * 4 + wave;
  const float* g = Gg + (size_t)t * 128;
  const float g1 = g[lane], g2 = g[lane + 64];
  float s1 = g1 * g1, s2 = g2 * g2;
#pragma unroll
  for (int off = 1; off < 16; off <<= 1) {
    s1 += __shfl_xor(s1, off, 64);
    s2 += __shfl_xor(s2, off, 64);
  }
  float lg[8];
#pragma unroll
  for (int e = 0; e < 4; ++e) {
    lg[e]     = sqrtf(__shfl(s1, e * 16, 64));
    lg[e + 4] = sqrtf(__shfl(s2, e * 16, 64));
  }
  int i1 = 0; float l1 = lg[0];
#pragma unroll
  for (int e = 1; e < 8; ++e) if (lg[e] > l1) { l1 = lg[e]; i1 = e; }
  int i2 = -1; float l2 = -1e30f;
#pragma unroll
  for (int e = 0; e < 8; ++e) if (e != i1 && lg[e] > l2) { l2 = lg[e]; i2 = e; }
  const float w1 = 1.f / (1.f + expf(l2 - l1));  // exact top-2 softmax renorm
  const float w2 = 1.f - w1;

  bf16* a2 = A2 + (size_t)t * A2C;
#pragma unroll
  for (int c0 = 0; c0 < A2C; c0 += 64) {
    const int c = c0 + lane;
    float v;
    if (c < 256) {
      const int we = c >> 5;
      const float wsel = (we == i1) ? w1 : ((we == i2) ? w2 : 0.f);
      v = (float)a2[c] * wsel;   // z (bf16, written by z-GEMM) scaled in place
    } else if (c < 264) {
      const int we = c - 256;
      v = (we == i1) ? w1 : ((we == i2) ? w2 : 0.f);
    } else if (c == 264) {
      v = 1.f;
    } else {
      v = 0.f;
    }
    a2[c] = (bf16)v;
  }
}

extern "C" void kernel_launch(void* const* d_in, const int* in_sizes, int n_in,
                              void* d_out, int out_size, void* d_ws, size_t ws_size,
                              hipStream_t stream) {
  // size-based dispatch; u/svh share 524288: first = u, second = svh (dict order)
  const float *x = nullptr, *W = nullptr, *b = nullptr, *gw = nullptr;
  const float *u = nullptr, *svh = nullptr, *eb = nullptr;
  int seen524 = 0;
  for (int i = 0; i < n_in; ++i) {
    switch (in_sizes[i]) {
      case 16777216: x  = (const float*)d_in[i]; break;
      case 4194304:  W  = (const float*)d_in[i]; break;
      case 2048:     b  = (const float*)d_in[i]; break;
      case 262144:   gw = (const float*)d_in[i]; break;
      case 524288:   if (seen524++ == 0) u = (const float*)d_in[i];
                     else                svh = (const float*)d_in[i];
                     break;
      case 16384:    eb = (const float*)d_in[i]; break;
      default: break;  // top_k (size 1)
    }
  }
  float* out = (float*)d_out;   // fp32 output (confirmed round 6)

  char* ws = (char*)d_ws;
  bf16*  xb = (bf16*)(ws + WS_XB);
  float* Gg = (float*)(ws + WS_GG);
  bf16*  A2 = (bf16*)(ws + WS_A2);
  bf16*  B2 = (bf16*)(ws + WS_B2);
  bf16*  Wz = (bf16*)(ws + WS_WZ);
  bf16*  Wb = (bf16*)(ws + WS_WB);

  prep_kernel<<<1024, 256, 0, stream>>>(x, W, svh, u, eb, b, xb, Wb, Wz, B2);

  // gate logits: zero accumulator, split-K x4 fp32 GEMM with atomic epilogue
  hipMemsetAsync(Gg, 0, (size_t)T_TOK * 128 * 4, stream);
  vgemm_gate<<<dim3(2, T_TOK / 64, GATE_KS), 256, 0, stream>>>(x, gw, Gg);

  // z = xb @ Wz^T -> bf16 directly into A2 cols 0..255 (ldc = 320)
  gemm_bt<64, 64, true><<<dim3(Z_COLS / 64, T_TOK / 64), 256, 0, stream>>>(
      xb, IN_F, xb, IN_F, Wz, IN_F, Wz, IN_F, (void*)A2, A2C, IN_F, IN_F);

  router_kernel<<<T_TOK / 4, 256, 0, stream>>>(Gg, A2);

  // out = [xb | A2] @ [Wb | B2]^T  (pre + moe + both biases fused), fp32 store
  gemm_bt<128, 128, false><<<dim3(OUT_F / 128, T_TOK / 128), 256, 0, stream>>>(
      xb, IN_F, A2, A2C, Wb, IN_F, B2, A2C, (void*)out, OUT_F, IN_F, K2_TOT);
}